// Round 3
// baseline (1713.348 us; speedup 1.0000x reference)
//
#include <hip/hip_runtime.h>
#include <hip/hip_bf16.h>

// LIF fused kernel, Round 3.
// Inputs fp32 (R1 NaN proved): spikes [T,B,F] {0,1}, W [F,F].
// Outputs FP32 (R2 absmax 2.7 > 1.0 proved output-0 region held non-z data
// when writing bf16): concat z_last, v, i (each [B,F] fp32).
//
// Numerics: 3-term split W = Whi+Wmid+Wlo (bf16 RNE each) captures 24
// mantissa bits -> x residual ~2^-27|W|; remaining error is fp32 summation
// -order noise (~1e-7), below threshold-flip significance.
// Spikes are exactly {0,1}: bf16 truncation (high 16 bits) is exact.
//
// Tiling: 256 blocks x 256 thr (4 waves). Block = 16 b-rows x 32 g-cols.
// Waves: (gh = g-half of 16, kh = K-half of 256). Per t: stage fp32 16x512
// spike slab -> bf16 LDS (truncation pack), each wave MFMAs its K-half with
// register-resident Whi/Wmid/Wlo frags (96 VGPRs), kh partials combined via
// LDS, LIF state fp32 in kh==0 waves (MFMA C-layout). Next-t slab prefetched
// into registers right after barrier1 so L2 latency hides under MFMA.
// blockIdx%16 = b_tile -> all 16 g-blocks of a b-tile on one XCD (bid%8).

typedef __attribute__((ext_vector_type(8))) short short8;   // 8 x bf16
typedef __attribute__((ext_vector_type(4))) float floatx4;
typedef __attribute__((ext_vector_type(2))) unsigned uintx2;

#define T_STEPS 1024
#define B_DIM   256
#define F_DIM   512
#define BF      (B_DIM * F_DIM)
#define ROWP    520   // padded LDS row (bf16 units); 1040B = 16B-aligned rows

static __device__ __forceinline__ unsigned short f2bf_rne(float f) {
    unsigned u = __float_as_uint(f);
    return (unsigned short)((u + 0x7FFFu + ((u >> 16) & 1u)) >> 16);
}
static __device__ __forceinline__ float bf2f(unsigned short h) {
    return __uint_as_float(((unsigned)h) << 16);
}

__global__ __launch_bounds__(256, 1)
void lif_kernel(const float* __restrict__ spikes,
                const float* __restrict__ W,
                float* __restrict__ out)
{
    __shared__ unsigned short sA[16 * ROWP];   // staged bf16 A-slab
    __shared__ float xbuf[2 * 256];            // kh=1 partial x per g-half

    const int tid  = threadIdx.x;
    const int lane = tid & 63;
    const int w    = tid >> 6;      // 0..3
    const int gh   = w & 1;         // g-half within block
    const int kh   = w >> 1;        // K-half
    const int bt   = blockIdx.x & 15;
    const int gb   = blockIdx.x >> 4;
    const int b0   = bt * 16;
    const int gw   = gb * 32 + gh * 16;   // wave's g-base
    const int mrow = lane & 15;
    const int kq   = lane >> 4;

    // ---- W fragments (once): rows gw+mrow, k in kh*256 + ks*32 + kq*8 + j
    short8 whi[8], wmd[8], wlo[8];
    {
        const float* wp = W + (size_t)(gw + mrow) * F_DIM + kh * 256 + kq * 8;
        #pragma unroll
        for (int ks = 0; ks < 8; ++ks) {
            short8 hi, md, lo;
            #pragma unroll
            for (int j = 0; j < 8; ++j) {
                float f = wp[ks * 32 + j];
                unsigned short h = f2bf_rne(f);
                float r1 = f - bf2f(h);
                unsigned short m = f2bf_rne(r1);
                float r2 = r1 - bf2f(m);
                hi[j] = (short)h;
                md[j] = (short)m;
                lo[j] = (short)f2bf_rne(r2);
            }
            whi[ks] = hi; wmd[ks] = md; wlo[ks] = lo;
        }
    }

    // ---- LIF state (kh==0 waves), C-layout: b = b0+kq*4+r, g = gw+mrow
    float v[4]  = {0.f, 0.f, 0.f, 0.f};
    float cu[4] = {0.f, 0.f, 0.f, 0.f};
    float zf[4] = {0.f, 0.f, 0.f, 0.f};

    // staging: thread covers float4 q = tid + 256*j; row = q>>7, col4 = q&127
    floatx4 ld[8];
    auto issue_loads = [&](int t) {
        const floatx4* sp = (const floatx4*)(spikes + (size_t)t * BF + (size_t)b0 * F_DIM);
        #pragma unroll
        for (int j = 0; j < 8; ++j)
            ld[j] = sp[tid + 256 * j];
    };

    issue_loads(0);
    for (int t = 0; t < T_STEPS; ++t) {
        // convert prefetched slab -> bf16 LDS (truncation: spikes are exact)
        #pragma unroll
        for (int j = 0; j < 8; ++j) {
            const int q = tid + 256 * j;
            const int row = q >> 7, col4 = q & 127;
            unsigned u0 = __float_as_uint(ld[j][0]);
            unsigned u1 = __float_as_uint(ld[j][1]);
            unsigned u2 = __float_as_uint(ld[j][2]);
            unsigned u3 = __float_as_uint(ld[j][3]);
            uintx2 d;
            d[0] = (u0 >> 16) | (u1 & 0xFFFF0000u);
            d[1] = (u2 >> 16) | (u3 & 0xFFFF0000u);
            *(uintx2*)&sA[row * ROWP + col4 * 4] = d;
        }
        __syncthreads();                          // barrier1: sA(t) ready
        if (t + 1 < T_STEPS) issue_loads(t + 1);  // hide L2 latency under MFMA

        floatx4 ah = {0.f, 0.f, 0.f, 0.f};
        floatx4 am = {0.f, 0.f, 0.f, 0.f};
        floatx4 al = {0.f, 0.f, 0.f, 0.f};
        const unsigned short* arow = &sA[mrow * ROWP + kh * 256 + kq * 8];
        #pragma unroll
        for (int ks = 0; ks < 8; ++ks) {
            short8 a = *(const short8*)(arow + ks * 32);
            ah = __builtin_amdgcn_mfma_f32_16x16x32_bf16(a, whi[ks], ah, 0, 0, 0);
            am = __builtin_amdgcn_mfma_f32_16x16x32_bf16(a, wmd[ks], am, 0, 0, 0);
            al = __builtin_amdgcn_mfma_f32_16x16x32_bf16(a, wlo[ks], al, 0, 0, 0);
        }

        if (kh == 1) {
            floatx4 xp = (ah + am) + al;
            *(floatx4*)&xbuf[gh * 256 + lane * 4] = xp;
        }
        __syncthreads();                          // barrier2: xbuf ready
        if (kh == 0) {
            floatx4 other = *(const floatx4*)&xbuf[gh * 256 + lane * 4];
            #pragma unroll
            for (int r = 0; r < 4; ++r) {
                float x    = ((ah[r] + am[r]) + al[r]) + other[r];
                float vdec = v[r] + 0.1f * ((0.0f - v[r]) + cu[r]);  // DT*TAU_MEM_INV
                float idec = cu[r] - 0.2f * cu[r];                    // DT*TAU_SYN_INV
                bool  spk  = (vdec - 1.0f) > 0.0f;                    // heaviside
                zf[r] = spk ? 1.0f : 0.0f;
                v[r]  = spk ? 0.0f : vdec;                            // V_RESET = 0
                cu[r] = idec + x;
            }
        }
        // next-iter barrier1 orders kh0's xbuf read before kh1's next write,
        // and sA(t) frag reads (pre-barrier2) before sA(t+1) stores.
    }

    if (kh == 0) {
        #pragma unroll
        for (int r = 0; r < 4; ++r) {
            const size_t idx = (size_t)(b0 + kq * 4 + r) * F_DIM + gw + mrow;
            out[idx]          = zf[r];
            out[BF + idx]     = v[r];
            out[2 * BF + idx] = cu[r];
        }
    }
}

extern "C" void kernel_launch(void* const* d_in, const int* in_sizes, int n_in,
                              void* d_out, int out_size, void* d_ws, size_t ws_size,
                              hipStream_t stream)
{
    const float* spikes = (const float*)d_in[0];   // [T,B,F] fp32
    const float* W      = (const float*)d_in[1];   // [F,F]   fp32
    float* out          = (float*)d_out;           // [3,B,F] fp32

    lif_kernel<<<dim3(256), dim3(256), 0, stream>>>(spikes, W, out);
}